// Round 5
// baseline (148.743 us; speedup 1.0000x reference)
//
#include <hip/hip_runtime.h>

typedef unsigned long long u64;

#define FLAG_M1 0x13579BDFu
#define FLAG_M2 0x2468ACE1u

__device__ __forceinline__ int find_root(int* L, int a){
    int p = L[a];
    while(p != a){
        int gp = L[p];
        if(gp != p) L[a] = gp;   // path halving; benign race
        a = p; p = gp;
    }
    return a;
}

// Link-by-index (root hi -> lo): links strictly decrease => acyclic under
// concurrency. Every successful CAS merges exactly two distinct trees, so
// b0 = total_runs - sum(successes): no arena scan needed (order-invariant).
__device__ __forceinline__ int unite(int* L, int a, int b){
    while(true){
        a = find_root(L, a);
        b = find_root(L, b);
        if(a == b) return 0;
        int hi = (a > b) ? a : b;
        int lo = (a > b) ? b : a;
        int old = atomicCAS(&L[hi], hi, lo);
        if(old == hi) return 1;
        a = old; b = lo;
    }
}

// One block per (ch, threshold, region). Thread w builds u64 row-half-word w
// from 16 float4 loads. pix/edges via popcounts. Union-find over RUNS with
// compact ids. b0 = runs - merges.
// ROUND-5: unites processed in 7 HIERARCHICAL LEVELS (boundary row k at level
// ctz(k): binary merge tree over rows -- disjoint band-pair merges, so no
// concurrently-built long chains), with two pointer-jump flattening sweeps
// between levels so every find is ~3-4 hops. Attacks the lockstep
// max-chain-depth cost identified as the wall in rounds 3-4.
__device__ __forceinline__ void ccl_body(const float* __restrict__ prob,
                                         const int*   __restrict__ sel,
                                         float*       __restrict__ betti,
                                         unsigned*    __restrict__ flags,
                                         float*       __restrict__ out,
                                         u64* M, u64* S, int* Pr, int* L, int* red,
                                         int tid, int bid){
    if(bid == 0 && tid == 0) atomicExch(out, 0.0f);   // zero for rows' atomicAdd
    const int ch = bid / 400, t = (bid % 400) >> 2, r = bid & 3;
    const float th = (float)t / 99.0f;
    const float* img = prob + (size_t)(sel[r] * 3 + ch) * 16384;

    // per-thread word build: thread w owns pixels [64w, 64w+64)
    const int w = tid;
    {
        const float4* imgv = (const float4*)img;
        u64 mw = 0ULL;
        #pragma unroll
        for(int k = 0; k < 16; k++){
            const float4 v = imgv[w * 16 + k];
            const unsigned nib = (unsigned)(v.x > th)
                               | ((unsigned)(v.y > th) << 1)
                               | ((unsigned)(v.z > th) << 2)
                               | ((unsigned)(v.w > th) << 3);
            mw |= (u64)nib << (4 * k);
        }
        M[w] = mw;
    }
    __syncthreads();                                       // B1: M complete

    // per-word masks & counts (thread <-> word)
    const int lane = tid & 63, wave = tid >> 6;
    const int row = w >> 1, half = w & 1;
    const u64 m = M[w];
    const u64 lcar = half ? (M[w - 1] >> 63) : 0ULL;
    const u64 s = m & ~((m << 1) | lcar);
    S[w] = s;
    int pix   = __popcll(m);
    int edges = __popcll(m & ((m << 1) | lcar));           // horizontal pairs
    const u64 va = (row > 0) ? M[w - 2] : 0ULL;
    edges += __popcll(m & va);                              // vertical pairs
    const int runs = __popcll(s);
    u64 csm = 0ULL;                                         // vertical contact-segment starts
    if(row > 0){
        const u64 c = m & va;
        const u64 ccar = half ? ((M[w - 1] & M[w - 3]) >> 63) : 0ULL;
        csm = c & ~((c << 1) | ccar);
    }

    // exclusive prefix sum of runs over the 256 words -> compact run ids
    int incl = runs;
    for(int off = 1; off < 64; off <<= 1){
        int n = __shfl_up(incl, off, 64);
        if(lane >= off) incl += n;
    }
    if(lane == 63) red[wave] = incl;
    __syncthreads();                                       // B2: S + wave totals
    int woff = 0;
    for(int k = 0; k < wave; k++) woff += red[k];
    const int excl = woff + incl - runs;                   // == Pr[w]
    Pr[w] = excl;
    if(w == 255) Pr[256] = excl + runs;
    const u64 sa = (row > 0) ? S[w - 2] : 0ULL;            // S stable after B2
    __syncthreads();                                       // B3: Pr complete
    const int R = Pr[256];
    const int Pa = (row > 0) ? Pr[w - 2] : 0;

    {   // arena init: only the R live nodes (rounded up to int4)
        int4* L4 = (int4*)L;
        const int n4 = (R + 3) >> 2;
        for(int i = tid; i < n4; i += 256){ int b = i * 4; L4[i] = make_int4(b, b+1, b+2, b+3); }
    }
    __syncthreads();                                       // B4: arena ready

    // unite phase, 7 levels: level l handles boundary rows with ctz(row)==l.
    // Merge count is order-invariant (successes always == R - #components),
    // so the reordering is exact. Between levels, 2 pointer-jump sweeps keep
    // all trees depth<=~4 -> finds are short and uniform across the wave.
    int merges = 0;
    const int lvl = (row > 0) ? __builtin_ctz(row) : 7;
    #pragma unroll 1
    for(int l = 0; l < 7; l++){
        if(lvl == l){
            u64 cs = csm;
            while(cs){
                const int x = __ffsll(cs) - 1;
                cs &= cs - 1;
                const u64 lm = (2ULL << x) - 1;            // bits [0..x]
                const int nb = excl + __popcll(s  & lm) - 1;
                const int na = Pa   + __popcll(sa & lm) - 1;
                merges += unite(L, na, nb);
            }
        }
        __syncthreads();                                   // level l done
        if(l < 6){
            // two flattening sweeps (parallel, coalesced reads; writing any
            // ancestor is always safe -- links only decrease)
            for(int i = tid; i < R; i += 256){ const int p = L[i]; const int gp = L[p]; if(gp != p) L[i] = gp; }
            __syncthreads();
            for(int i = tid; i < R; i += 256){ const int p = L[i]; const int gp = L[p]; if(gp != p) L[i] = gp; }
            __syncthreads();                               // flat arena for level l+1
        }
    }

    int v0 = pix, v1 = edges, v2 = merges;
    for(int off = 32; off; off >>= 1){
        v0 += __shfl_down(v0, off, 64);
        v1 += __shfl_down(v1, off, 64);
        v2 += __shfl_down(v2, off, 64);
    }
    __syncthreads();                                       // B5: red[] reusable
    if(lane == 0){ red[wave*3] = v0; red[wave*3+1] = v1; red[wave*3+2] = v2; }
    __syncthreads();
    if(tid == 0){
        int P = 0, E = 0, MG = 0;
        for(int k = 0; k < 4; k++){ P += red[k*3]; E += red[k*3+1]; MG += red[k*3+2]; }
        const float b0f = (float)(R - MG);                 // components = nodes - links
        const float b1f = b0f - ((float)P - (float)E);     // b1 = b0 - (pix - edges)
        const size_t o = (((size_t)ch * 100 + t) * 4 + r) * 2;
        // agent-scope (device-coherent) stores: visible across XCDs
        __hip_atomic_store(&betti[o],     b0f, __ATOMIC_RELAXED, __HIP_MEMORY_SCOPE_AGENT);
        __hip_atomic_store(&betti[o + 1], b1f, __ATOMIC_RELAXED, __HIP_MEMORY_SCOPE_AGENT);
        // publish: two DIFFERENT magics 16B apart => a repeated poison fill
        // pattern (period 1/2/4/8/16B) can never forge both.
        unsigned* f = flags + (size_t)bid * 8;
        __hip_atomic_store(&f[0], FLAG_M1, __ATOMIC_RELEASE, __HIP_MEMORY_SCOPE_AGENT);
        __hip_atomic_store(&f[4], FLAG_M2, __ATOMIC_RELEASE, __HIP_MEMORY_SCOPE_AGENT);
    }
}

// One (region, code-column) row per block; accumulates into out[0]
// (zeroed by ccl block 0 before its flag is set) with a device-scope
// float atomicAdd. fsh must point at >= 801 floats of shared memory.
__device__ __forceinline__ void rows_body(const float* __restrict__ betti,
                                          const float* __restrict__ gt,
                                          float*       __restrict__ out,
                                          int row, int tid, float* fsh){
    float* codes = fsh;            // [100]
    float* birth = fsh + 100;      // [99]
    float* bs0   = fsh + 199;      // [99]
    float* bs1   = fsh + 298;      // [99]
    float* gs0   = fsh + 397;      // [99]
    float* gs1   = fsh + 496;      // [99]
    float* gsh   = fsh + 595;      // [198]
    float* redf  = fsh + 793;      // [8]
    const int r = row / 6, j = row % 6;
    const int chmap[6] = {0, 0, 1, 1, 0, 0};   // inside, boundary, union(=inside)
    const int ch = chmap[j], comp = j & 1;

    if(tid < 100)
        codes[tid] = __hip_atomic_load(&betti[(((size_t)ch * 100 + tid) * 4 + r) * 2 + comp],
                                       __ATOMIC_RELAXED, __HIP_MEMORY_SCOPE_AGENT);
    const float* g = gt + (size_t)row * 198;
    for(int i = tid; i < 198; i += 256) gsh[i] = g[i];
    __syncthreads();

    float b = 0.f, d = 0.f;
    if(tid < 99){
        const float dv = codes[tid + 1] - codes[tid];
        const float thv = (float)tid / 99.0f;
        b = (dv > 0.f) ? thv : 0.f;
        d = (dv < 0.f) ? thv : 0.f;
        birth[tid] = b;
    }
    __syncthreads();

    if(tid < 99){
        // stable sort by birth == stable partition (positive births already ascending)
        int zb = 0, tz = 0;
        for(int k = 0; k < 99; k++){
            const int z = (birth[k] == 0.f) ? 1 : 0;
            tz += z;
            if(k < tid) zb += z;
        }
        const int pos = (b == 0.f) ? zb : (tz + tid - zb);
        bs0[pos] = b; bs1[pos] = d;

        const float gb = gsh[tid * 2];
        int rank = 0;
        for(int k = 0; k < 99; k++){
            const float o = gsh[k * 2];
            rank += (o < gb || (o == gb && k < tid)) ? 1 : 0;
        }
        gs0[rank] = gb; gs1[rank] = gsh[tid * 2 + 1];
    }
    __syncthreads();

    float mm = 0.f, u = 0.f;
    if(tid < 99){
        mm = fabsf(bs0[tid] - gs0[tid]) + fabsf(bs1[tid] - gs1[tid]);
        u = d - b;
    }
    for(int off = 32; off; off >>= 1){
        mm += __shfl_down(mm, off, 64);
        u  += __shfl_down(u,  off, 64);
    }
    if((tid & 63) == 0){ redf[(tid >> 6) * 2] = mm; redf[(tid >> 6) * 2 + 1] = u; }
    __syncthreads();
    if(tid == 0)
        atomicAdd(out, (redf[0] + redf[2] + redf[4] + redf[6]) / 2376.0f
                     + (redf[1] + redf[3] + redf[5] + redf[7]) / 24.0f);
}

// Fused single dispatch, NO grid sync: blocks 0..799 = ccl producers,
// blocks 800..823 = rows consumers that spin only on their own 100 producer
// flags (+ block 0's flag, which guards the out-zeroing).
// Deadlock-free: only 24 consumer blocks can ever spin; producers always
// have slots to make progress (824 blocks <= 1280 co-resident slots anyway).
__global__ __launch_bounds__(256) void fused_kernel(const float* __restrict__ prob,
                                                    const int*   __restrict__ sel,
                                                    const float* __restrict__ gt,
                                                    float*       __restrict__ betti,
                                                    unsigned*    __restrict__ flags,
                                                    float*       __restrict__ out){
    __shared__ u64 M[256];     // row masks: word w = (row<<1)|half
    __shared__ u64 S[256];     // run-start masks
    __shared__ int Pr[257];    // exclusive prefix of per-word run counts
    __shared__ int L[6400];    // union-find arena (25.6 KB); reused as rows scratch
    __shared__ int red[12];
    const int tid = threadIdx.x, bid = blockIdx.x;

    if(bid < 800){
        ccl_body(prob, sel, betti, flags, out, M, S, Pr, L, red, tid, bid);
        return;
    }

    // ---- consumer block: one barcode row ----
    const int row = bid - 800;
    const int r = row / 6, j = row % 6;
    const int chmap[6] = {0, 0, 1, 1, 0, 0};
    const int ch = chmap[j];

    if(tid <= 100){
        // tid<100: producer (ch, t=tid, r). tid==100: block 0 (out zeroed).
        const int pb = (tid < 100) ? (ch * 400 + tid * 4 + r) : 0;
        unsigned* f = flags + (size_t)pb * 8;
        while(__hip_atomic_load(&f[0], __ATOMIC_ACQUIRE, __HIP_MEMORY_SCOPE_AGENT) != FLAG_M1 ||
              __hip_atomic_load(&f[4], __ATOMIC_ACQUIRE, __HIP_MEMORY_SCOPE_AGENT) != FLAG_M2){
            __builtin_amdgcn_s_sleep(8);
        }
    }
    __syncthreads();           // all producers for this row are done & visible

    rows_body(betti, gt, out, row, tid, (float*)L);
}

extern "C" void kernel_launch(void* const* d_in, const int* in_sizes, int n_in,
                              void* d_out, int out_size, void* d_ws, size_t ws_size,
                              hipStream_t stream){
    const float* prob = (const float*)d_in[0];   // [4,3,128,128] f32
    const int*   sel  = (const int*)d_in[1];     // [4]
    const float* gt   = (const float*)d_in[2];   // [4,6,99,2] f32
    float*    betti = (float*)d_ws;                              // 1600 floats
    unsigned* flags = (unsigned*)((char*)d_ws + 8192);           // 800 pairs x 32B

    fused_kernel<<<824, 256, 0, stream>>>(prob, sel, gt, betti, flags, (float*)d_out);
}

// Round 6
// 93.829 us; speedup vs baseline: 1.5853x; 1.5853x over previous
//
#include <hip/hip_runtime.h>

typedef unsigned long long u64;

#define FLAG_M1 0x13579BDFu
#define FLAG_M2 0x2468ACE1u
#define WL_CAP  4928

__device__ __forceinline__ int find_root(int* L, int a){
    int p = L[a];
    while(p != a){
        int gp = L[p];
        if(gp != p) L[a] = gp;   // path halving; benign race
        a = p; p = gp;
    }
    return a;
}

// Link-by-index (root hi -> lo): links strictly decrease => acyclic under
// concurrency. Every successful CAS merges exactly two distinct trees, so
// b0 = total_runs - sum(successes), order-invariant: no arena scan needed.
__device__ __forceinline__ int unite(int* L, int a, int b){
    while(true){
        a = find_root(L, a);
        b = find_root(L, b);
        if(a == b) return 0;
        int hi = (a > b) ? a : b;
        int lo = (a > b) ? b : a;
        int old = atomicCAS(&L[hi], hi, lo);
        if(old == hi) return 1;
        a = old; b = lo;
    }
}

// One block per (ch, threshold, region). Thread w builds u64 row-half-word w
// from 16 float4 loads. pix/edges via popcounts. Union-find over RUNS.
// ROUND-6: contact segments are flattened into a shared WORKLIST (packed
// 13+13-bit pairs), then all 256 threads grid-stride it with the proven R2
// unite engine. This removes the per-lane lockstep imbalance (0..30 segs per
// lane) that rounds 3-5 indicted: rounds = ceil(K/256) at average cost, not
// max-per-lane at max cost. Dual prefix sum carried in one packed shfl scan.
__device__ __forceinline__ void ccl_body(const float* __restrict__ prob,
                                         const int*   __restrict__ sel,
                                         float*       __restrict__ betti,
                                         unsigned*    __restrict__ flags,
                                         float*       __restrict__ out,
                                         u64* M, u64* S, int* Pr, int* L,
                                         unsigned* WL, int* red,
                                         int tid, int bid){
    if(bid == 0 && tid == 0) atomicExch(out, 0.0f);   // zero for rows' atomicAdd
    const int ch = bid / 400, t = (bid % 400) >> 2, r = bid & 3;
    const float th = (float)t / 99.0f;
    const float* img = prob + (size_t)(sel[r] * 3 + ch) * 16384;

    // per-thread word build: thread w owns pixels [64w, 64w+64)
    const int w = tid;
    {
        const float4* imgv = (const float4*)img;
        u64 mw = 0ULL;
        #pragma unroll
        for(int k = 0; k < 16; k++){
            const float4 v = imgv[w * 16 + k];
            const unsigned nib = (unsigned)(v.x > th)
                               | ((unsigned)(v.y > th) << 1)
                               | ((unsigned)(v.z > th) << 2)
                               | ((unsigned)(v.w > th) << 3);
            mw |= (u64)nib << (4 * k);
        }
        M[w] = mw;
    }
    __syncthreads();                                       // B1: M complete

    // per-word masks & counts (thread <-> word)
    const int lane = tid & 63, wave = tid >> 6;
    const int row = w >> 1, half = w & 1;
    const u64 m = M[w];
    const u64 lcar = half ? (M[w - 1] >> 63) : 0ULL;
    const u64 s = m & ~((m << 1) | lcar);
    S[w] = s;
    int pix   = __popcll(m);
    int edges = __popcll(m & ((m << 1) | lcar));           // horizontal pairs
    const u64 va = (row > 0) ? M[w - 2] : 0ULL;
    edges += __popcll(m & va);                              // vertical pairs
    const int runs = __popcll(s);
    u64 csm = 0ULL;                                         // vertical contact-segment starts
    if(row > 0){
        const u64 c = m & va;
        const u64 ccar = half ? ((M[w - 1] & M[w - 3]) >> 63) : 0ULL;
        csm = c & ~((c << 1) | ccar);
    }
    const int nseg = __popcll(csm);

    // packed dual prefix sum over 256 words: low16 = runs, high16 = segs
    // (both totals < 2^16, so halves never carry into each other)
    const int packed = runs | (nseg << 16);
    int incl = packed;
    for(int off = 1; off < 64; off <<= 1){
        int n = __shfl_up(incl, off, 64);
        if(lane >= off) incl += n;
    }
    if(lane == 63) red[wave] = incl;
    __syncthreads();                                       // B2: S + wave totals
    int woff = 0;
    for(int k = 0; k < wave; k++) woff += red[k];
    const int exclP = woff + incl - packed;
    Pr[w] = exclP;
    if(w == 255) Pr[256] = exclP + packed;
    const u64 sa = (row > 0) ? S[w - 2] : 0ULL;            // S stable after B2
    __syncthreads();                                       // B3: Pr complete
    const int RK = Pr[256];
    const int R  = RK & 0xFFFF;                            // total runs
    const int K  = (int)((unsigned)RK >> 16);              // total contact segs
    const int excl  = exclP & 0xFFFF;
    const int sexcl = (int)((unsigned)exclP >> 16);
    const int Pa = (row > 0) ? (Pr[w - 2] & 0xFFFF) : 0;

    {   // arena init: only the R live nodes (rounded up to int4)
        int4* L4 = (int4*)L;
        const int n4 = (R + 3) >> 2;
        for(int i = tid; i < n4; i += 256){ int b = i * 4; L4[i] = make_int4(b, b+1, b+2, b+3); }
    }
    {   // worklist write: this word's segments land at [sexcl, sexcl+nseg)
        int slot = sexcl;
        u64 cs = csm;
        while(cs && slot < WL_CAP){
            const int x = __ffsll(cs) - 1;
            cs &= cs - 1;
            const u64 lm = (2ULL << x) - 1;                // bits [0..x]
            const int nb = excl + __popcll(s  & lm) - 1;
            const int na = Pa   + __popcll(sa & lm) - 1;
            WL[slot++] = ((unsigned)na << 13) | (unsigned)nb;
        }
    }
    __syncthreads();                                       // B4: arena + WL ready

    // evenly-distributed unite over the worklist
    int merges = 0;
    {
        const int KC = (K < WL_CAP) ? K : WL_CAP;
        for(int i = tid; i < KC; i += 256){
            const unsigned e = WL[i];
            merges += unite(L, (int)(e >> 13), (int)(e & 0x1FFFu));
        }
        if(K > WL_CAP){                                    // overflow: direct path
            u64 cs = csm; int idx = sexcl;
            while(cs){
                const int x = __ffsll(cs) - 1;
                cs &= cs - 1;
                if(idx >= WL_CAP){
                    const u64 lm = (2ULL << x) - 1;
                    const int nb = excl + __popcll(s  & lm) - 1;
                    const int na = Pa   + __popcll(sa & lm) - 1;
                    merges += unite(L, na, nb);
                }
                idx++;
            }
        }
    }

    int v0 = pix, v1 = edges, v2 = merges;
    for(int off = 32; off; off >>= 1){
        v0 += __shfl_down(v0, off, 64);
        v1 += __shfl_down(v1, off, 64);
        v2 += __shfl_down(v2, off, 64);
    }
    __syncthreads();                                       // B5: red[] reusable
    if(lane == 0){ red[wave*3] = v0; red[wave*3+1] = v1; red[wave*3+2] = v2; }
    __syncthreads();
    if(tid == 0){
        int P = 0, E = 0, MG = 0;
        for(int k = 0; k < 4; k++){ P += red[k*3]; E += red[k*3+1]; MG += red[k*3+2]; }
        const float b0f = (float)(R - MG);                 // components = nodes - links
        const float b1f = b0f - ((float)P - (float)E);     // b1 = b0 - (pix - edges)
        const size_t o = (((size_t)ch * 100 + t) * 4 + r) * 2;
        // agent-scope (device-coherent) stores: visible across XCDs
        __hip_atomic_store(&betti[o],     b0f, __ATOMIC_RELAXED, __HIP_MEMORY_SCOPE_AGENT);
        __hip_atomic_store(&betti[o + 1], b1f, __ATOMIC_RELAXED, __HIP_MEMORY_SCOPE_AGENT);
        // publish: two DIFFERENT magics 16B apart => a repeated poison fill
        // pattern (period 1/2/4/8/16B) can never forge both.
        unsigned* f = flags + (size_t)bid * 8;
        __hip_atomic_store(&f[0], FLAG_M1, __ATOMIC_RELEASE, __HIP_MEMORY_SCOPE_AGENT);
        __hip_atomic_store(&f[4], FLAG_M2, __ATOMIC_RELEASE, __HIP_MEMORY_SCOPE_AGENT);
    }
}

// One (region, code-column) row per block; accumulates into out[0]
// (zeroed by ccl block 0 before its flag is set) with a device-scope
// float atomicAdd. fsh must point at >= 801 floats of shared memory.
__device__ __forceinline__ void rows_body(const float* __restrict__ betti,
                                          const float* __restrict__ gt,
                                          float*       __restrict__ out,
                                          int row, int tid, float* fsh){
    float* codes = fsh;            // [100]
    float* birth = fsh + 100;      // [99]
    float* bs0   = fsh + 199;      // [99]
    float* bs1   = fsh + 298;      // [99]
    float* gs0   = fsh + 397;      // [99]
    float* gs1   = fsh + 496;      // [99]
    float* gsh   = fsh + 595;      // [198]
    float* redf  = fsh + 793;      // [8]
    const int r = row / 6, j = row % 6;
    const int chmap[6] = {0, 0, 1, 1, 0, 0};   // inside, boundary, union(=inside)
    const int ch = chmap[j], comp = j & 1;

    if(tid < 100)
        codes[tid] = __hip_atomic_load(&betti[(((size_t)ch * 100 + tid) * 4 + r) * 2 + comp],
                                       __ATOMIC_RELAXED, __HIP_MEMORY_SCOPE_AGENT);
    const float* g = gt + (size_t)row * 198;
    for(int i = tid; i < 198; i += 256) gsh[i] = g[i];
    __syncthreads();

    float b = 0.f, d = 0.f;
    if(tid < 99){
        const float dv = codes[tid + 1] - codes[tid];
        const float thv = (float)tid / 99.0f;
        b = (dv > 0.f) ? thv : 0.f;
        d = (dv < 0.f) ? thv : 0.f;
        birth[tid] = b;
    }
    __syncthreads();

    if(tid < 99){
        // stable sort by birth == stable partition (positive births already ascending)
        int zb = 0, tz = 0;
        for(int k = 0; k < 99; k++){
            const int z = (birth[k] == 0.f) ? 1 : 0;
            tz += z;
            if(k < tid) zb += z;
        }
        const int pos = (b == 0.f) ? zb : (tz + tid - zb);
        bs0[pos] = b; bs1[pos] = d;

        const float gb = gsh[tid * 2];
        int rank = 0;
        for(int k = 0; k < 99; k++){
            const float o = gsh[k * 2];
            rank += (o < gb || (o == gb && k < tid)) ? 1 : 0;
        }
        gs0[rank] = gb; gs1[rank] = gsh[tid * 2 + 1];
    }
    __syncthreads();

    float mm = 0.f, u = 0.f;
    if(tid < 99){
        mm = fabsf(bs0[tid] - gs0[tid]) + fabsf(bs1[tid] - gs1[tid]);
        u = d - b;
    }
    for(int off = 32; off; off >>= 1){
        mm += __shfl_down(mm, off, 64);
        u  += __shfl_down(u,  off, 64);
    }
    if((tid & 63) == 0){ redf[(tid >> 6) * 2] = mm; redf[(tid >> 6) * 2 + 1] = u; }
    __syncthreads();
    if(tid == 0)
        atomicAdd(out, (redf[0] + redf[2] + redf[4] + redf[6]) / 2376.0f
                     + (redf[1] + redf[3] + redf[5] + redf[7]) / 24.0f);
}

// Fused single dispatch, NO grid sync: blocks 0..799 = ccl producers,
// blocks 800..823 = rows consumers that spin only on their own 100 producer
// flags (+ block 0's flag, which guards the out-zeroing).
// LDS ~50KB -> 3 blocks/CU -> 768 co-resident slots; only 24 blocks ever
// spin, so producers always have slots to make progress: deadlock-free.
__global__ __launch_bounds__(256) void fused_kernel(const float* __restrict__ prob,
                                                    const int*   __restrict__ sel,
                                                    const float* __restrict__ gt,
                                                    float*       __restrict__ betti,
                                                    unsigned*    __restrict__ flags,
                                                    float*       __restrict__ out){
    __shared__ u64 M[256];         // row masks: word w = (row<<1)|half
    __shared__ u64 S[256];         // run-start masks
    __shared__ int Pr[257];        // packed exclusive prefix (runs | segs<<16)
    __shared__ int L[6400];        // union-find arena (25.6 KB); rows scratch too
    __shared__ unsigned WL[WL_CAP];// packed edge worklist (na<<13|nb)
    __shared__ int red[12];
    const int tid = threadIdx.x, bid = blockIdx.x;

    if(bid < 800){
        ccl_body(prob, sel, betti, flags, out, M, S, Pr, L, WL, red, tid, bid);
        return;
    }

    // ---- consumer block: one barcode row ----
    const int row = bid - 800;
    const int r = row / 6, j = row % 6;
    const int chmap[6] = {0, 0, 1, 1, 0, 0};
    const int ch = chmap[j];

    if(tid <= 100){
        // tid<100: producer (ch, t=tid, r). tid==100: block 0 (out zeroed).
        const int pb = (tid < 100) ? (ch * 400 + tid * 4 + r) : 0;
        unsigned* f = flags + (size_t)pb * 8;
        while(__hip_atomic_load(&f[0], __ATOMIC_ACQUIRE, __HIP_MEMORY_SCOPE_AGENT) != FLAG_M1 ||
              __hip_atomic_load(&f[4], __ATOMIC_ACQUIRE, __HIP_MEMORY_SCOPE_AGENT) != FLAG_M2){
            __builtin_amdgcn_s_sleep(8);
        }
    }
    __syncthreads();           // all producers for this row are done & visible

    rows_body(betti, gt, out, row, tid, (float*)L);
}

extern "C" void kernel_launch(void* const* d_in, const int* in_sizes, int n_in,
                              void* d_out, int out_size, void* d_ws, size_t ws_size,
                              hipStream_t stream){
    const float* prob = (const float*)d_in[0];   // [4,3,128,128] f32
    const int*   sel  = (const int*)d_in[1];     // [4]
    const float* gt   = (const float*)d_in[2];   // [4,6,99,2] f32
    float*    betti = (float*)d_ws;                              // 1600 floats
    unsigned* flags = (unsigned*)((char*)d_ws + 8192);           // 800 pairs x 32B

    fused_kernel<<<824, 256, 0, stream>>>(prob, sel, gt, betti, flags, (float*)d_out);
}